// Round 3
// baseline (32.646 us; speedup 1.0000x reference)
//
#include <hip/hip_runtime.h>

#define NQ 4
#define DIM 16
#define NPAIR 136   // 16*17/2
#define ROWS 128    // batch rows per block

// ---------------------------------------------------------------------------
// Prep kernel (1 block x 256 threads): build U = full post-RY circuit unitary
// via shfl_xor butterflies (thread = (col, k), partner = lane^bit), then
// Apack[p*4+q] = packed upper-tri Re(U^T* Z_q U), off-diagonals doubled.
// ---------------------------------------------------------------------------
__global__ __launch_bounds__(256) void qnn_prep(const float* __restrict__ w,
                                                float* __restrict__ Apack) {
    __shared__ float Ure[DIM][DIM + 1];
    __shared__ float Uim[DIM][DIM + 1];
    const int tid = threadIdx.x;
    const int col = tid >> 4, k = tid & 15;

    float re = (k == col) ? 1.f : 0.f;
    float im = 0.f;

#pragma unroll
    for (int layer = 0; layer < 2; ++layer) {
#pragma unroll
        for (int q = 0; q < NQ; ++q) {
            const int bit = 1 << (3 - q);
            const int g = layer * NQ + q;
            // RZ(theta): amp *= e^{-i t/2} on bit==0, e^{+i t/2} on bit==1
            float sr, cr;
            sincosf(0.5f * w[g * 2 + 0], &sr, &cr);
            {
                const float ssr = (k & bit) ? -sr : sr;
                const float nre = re * cr + im * ssr;
                const float nim = im * cr - re * ssr;
                re = nre; im = nim;
            }
            // RY(theta): (a0,a1) -> (c a0 - s a1, s a0 + c a1); partner via shfl
            float sy, cy;
            sincosf(0.5f * w[g * 2 + 1], &sy, &cy);
            {
                const float pre = __shfl_xor(re, bit);
                const float pim = __shfl_xor(im, bit);
                const float se = (k & bit) ? sy : -sy;
                const float nre = cy * re + se * pre;
                const float nim = cy * im + se * pim;
                re = nre; im = nim;
            }
        }
        if (layer == 0) {
            // CNOT chain: control bit (3-c), target bit (2-c)
#pragma unroll
            for (int c = 0; c < 3; ++c) {
                const int cb = 1 << (3 - c), tb = 1 << (2 - c);
                const float pre = __shfl_xor(re, tb);
                const float pim = __shfl_xor(im, tb);
                const bool swap = (k & cb) != 0;
                re = swap ? pre : re;
                im = swap ? pim : im;
            }
        }
    }
    Ure[k][col] = re;
    Uim[k][col] = im;
    __syncthreads();

    // 544 dot-products (136 pairs x 4 outputs) over 256 threads
    for (int d = tid; d < NPAIR * 4; d += 256) {
        const int p = d >> 2, q = d & 3;
        int i = 0, j = 0, pp = p;
        for (i = 0; i < DIM; ++i) {
            const int row = DIM - i;
            if (pp < row) { j = i + pp; break; }
            pp -= row;
        }
        const float f = (i == j) ? 1.f : 2.f;
        float acc = 0.f;
#pragma unroll
        for (int kk = 0; kk < DIM; ++kk) {
            const float zq = ((kk >> (3 - q)) & 1) ? -1.f : 1.f;
            acc += zq * (Ure[kk][i] * Ure[kk][j] + Uim[kk][i] * Uim[kk][j]);
        }
        Apack[d] = f * acc;
    }
}

// ---------------------------------------------------------------------------
// Main kernel: 128 rows / 128 threads per block. x tile staged via
// global_load_lds (direct-to-LDS, no VGPR round-trip) into a LINEAR [128][64]
// f32 tile whose per-row float4-granules are rotated by the row index
// (pre-swizzled GLOBAL source address): granule slot s of row r holds source
// granule (s + r) & 15. Read of source granule t: slot (t - r) & 15 ->
// per-phase 2-way banks = conflict-free. Then GEMV + sincos + Kronecker +
// packed quadratic forms.
// ---------------------------------------------------------------------------
__global__ __launch_bounds__(128) void qnn_main(const float* __restrict__ x,
                                                const float* __restrict__ fm_w,
                                                const float* __restrict__ fm_b,
                                                const float* __restrict__ Apack,
                                                float* __restrict__ out, int B) {
    __shared__ float xs[ROWS * 64];   // 32 KiB, linear
    const int tid = threadIdx.x;
    const long long tile = (long long)blockIdx.x * ROWS;

    const float4* __restrict__ xg4 = (const float4*)x + tile * 16;
    const int wv_id = tid >> 6, l = tid & 63;
#pragma unroll
    for (int i = 0; i < 16; ++i) {
        const int j = wv_id * 16 + i;          // 1-KiB stage slot
        const int r = 4 * j + (l >> 4);        // tile row this lane feeds
        const int gsrc = ((l & 15) + r) & 15;  // rotated source granule
        const float4* src = xg4 + r * 16 + gsrc;
        float* dst = &xs[j * 256];             // wave-uniform LDS base
        __builtin_amdgcn_global_load_lds(
            (const __attribute__((address_space(1))) void*)src,
            (__attribute__((address_space(3))) void*)dst, 16, 0, 0);
    }
    __syncthreads();   // forces vmcnt(0): staged data visible

    const long long b = tile + tid;
    if (b < B) {
        // --- angles: 4 dot products of length 64 from LDS (row = tid) ---
        float acc[NQ];
#pragma unroll
        for (int q = 0; q < NQ; ++q) acc[q] = fm_b[q];

        const float4* __restrict__ w4 = (const float4*)fm_w;
#pragma unroll
        for (int t = 0; t < 16; ++t) {
            const int s = (t - tid) & 15;      // rotated slot of granule t
            const float4 xv = *(const float4*)&xs[tid * 64 + 4 * s];
#pragma unroll
            for (int q = 0; q < NQ; ++q) {
                const float4 wvq = w4[q * 16 + t];  // uniform -> s_load
                acc[q] += xv.x * wvq.x + xv.y * wvq.y + xv.z * wvq.z + xv.w * wvq.w;
            }
        }

        // --- per-qubit cos/sin of a/2 ---
        float c[NQ], s4[NQ];
#pragma unroll
        for (int q = 0; q < NQ; ++q) __sincosf(0.5f * acc[q], &s4[q], &c[q]);

        // --- product state via Kronecker tree (qubit 0 = MSB) ---
        float p01[4], p23[4];
#pragma unroll
        for (int u = 0; u < 4; ++u) {
            p01[u] = ((u & 2) ? s4[0] : c[0]) * ((u & 1) ? s4[1] : c[1]);
            p23[u] = ((u & 2) ? s4[2] : c[2]) * ((u & 1) ? s4[3] : c[3]);
        }
        float st[DIM];
#pragma unroll
        for (int i = 0; i < DIM; ++i) st[i] = p01[i >> 2] * p23[i & 3];

        // --- four quadratic forms over packed pairs (uniform -> s_load) ---
        float o0 = 0.f, o1 = 0.f, o2 = 0.f, o3 = 0.f;
        const float4* __restrict__ A4 = (const float4*)Apack;
        int p = 0;
#pragma unroll
        for (int i = 0; i < DIM; ++i) {
#pragma unroll
            for (int j = i; j < DIM; ++j) {
                const float pr = st[i] * st[j];
                const float4 aq = A4[p];
                o0 += aq.x * pr; o1 += aq.y * pr; o2 += aq.z * pr; o3 += aq.w * pr;
                ++p;
            }
        }

        *(float4*)(out + b * 4) = make_float4(o0, o1, o2, o3);
    }
}

extern "C" void kernel_launch(void* const* d_in, const int* in_sizes, int n_in,
                              void* d_out, int out_size, void* d_ws, size_t ws_size,
                              hipStream_t stream) {
    const float* x    = (const float*)d_in[0];
    const float* fm_w = (const float*)d_in[1];
    const float* fm_b = (const float*)d_in[2];
    const float* qw   = (const float*)d_in[3];
    float* out = (float*)d_out;
    float* Apack = (float*)d_ws;  // 136*4 floats = 2176 B

    const int B = in_sizes[0] / 64;

    qnn_prep<<<1, 256, 0, stream>>>(qw, Apack);
    qnn_main<<<(B + ROWS - 1) / ROWS, 128, 0, stream>>>(x, fm_w, fm_b, Apack, out, B);
}

// Round 4
// 24.799 us; speedup vs baseline: 1.3165x; 1.3165x over previous
//
#include <hip/hip_runtime.h>

#define NQ 4
#define DIM 16
#define NPAIR 136   // 16*17/2
#define TPB 512

// ---------------------------------------------------------------------------
// Fully fused kernel. Per block:
//   phase 0 (wave 0 only): build the constant 16x16 circuit unitary U via
//     shfl_xor butterflies (lane = (colgroup, k)), 4 columns per lane-pass;
//     gate sincos computed once (1 sincosf per lane, readlane-broadcast).
//   phase 1 (all 512 threads): Apack[p][q] = packed upper-tri Re(U^T* Z_q U),
//     off-diagonals doubled, into LDS (544 floats).
//   phase 2: one batch row per thread: angles GEMV (strided float4 loads --
//     measured fastest variant), __sincosf, Kronecker product state, four
//     quadratic forms against LDS Apack (uniform ds_read_b128 = broadcast).
// ---------------------------------------------------------------------------
__global__ __launch_bounds__(TPB, 4) void qnn_fused(
    const float* __restrict__ x, const float* __restrict__ fm_w,
    const float* __restrict__ fm_b, const float* __restrict__ w,
    float* __restrict__ out, int B) {
    __shared__ float Ure[DIM][DIM + 1];
    __shared__ float Uim[DIM][DIM + 1];
    __shared__ float ApackS[NPAIR * 4];

    const int tid = threadIdx.x;

    // ---- phase 0: wave 0 builds U into LDS ----
    if ((tid >> 6) == 0) {
        const int lane = tid & 63;
        const int k = lane & 15;
        // 16 gate params: g = layer*8 + q*2 + rot
        float sv, cv;
        sincosf(0.5f * w[k], &sv, &cv);
        float sp[16], cp[16];
#pragma unroll
        for (int g = 0; g < 16; ++g) { sp[g] = __shfl(sv, g); cp[g] = __shfl(cv, g); }

#pragma unroll
        for (int cc = 0; cc < 4; ++cc) {
            const int col = (lane >> 4) + 4 * cc;
            float re = (k == col) ? 1.f : 0.f, im = 0.f;
#pragma unroll
            for (int layer = 0; layer < 2; ++layer) {
#pragma unroll
                for (int q = 0; q < NQ; ++q) {
                    const int bit = 1 << (3 - q);
                    const int gz = layer * 8 + q * 2;
                    {   // RZ: amp *= e^{-i t/2} (bit=0) / e^{+i t/2} (bit=1)
                        const float s = sp[gz], c = cp[gz];
                        const float ssr = (k & bit) ? -s : s;
                        const float nre = re * c + im * ssr;
                        const float nim = im * c - re * ssr;
                        re = nre; im = nim;
                    }
                    {   // RY: partner via shfl_xor within 16-lane group
                        const float s = sp[gz + 1], c = cp[gz + 1];
                        const float pre = __shfl_xor(re, bit);
                        const float pim = __shfl_xor(im, bit);
                        const float se = (k & bit) ? s : -s;
                        re = c * re + se * pre;
                        im = c * im + se * pim;
                    }
                }
                if (layer == 0) {
                    // CNOT chain: control bit (3-c), target bit (2-c)
#pragma unroll
                    for (int c3 = 0; c3 < 3; ++c3) {
                        const int cb = 1 << (3 - c3), tb = 1 << (2 - c3);
                        const float pre = __shfl_xor(re, tb);
                        const float pim = __shfl_xor(im, tb);
                        if (k & cb) { re = pre; im = pim; }
                    }
                }
            }
            Ure[k][col] = re;
            Uim[k][col] = im;
        }
    }
    __syncthreads();

    // ---- phase 1: 544 observable dot-products into LDS Apack ----
    for (int d = tid; d < NPAIR * 4; d += TPB) {
        const int p = d >> 2, q = d & 3;
        int i = 0, j = 0, pp = p;
        for (i = 0; i < DIM; ++i) {
            const int row = DIM - i;
            if (pp < row) { j = i + pp; break; }
            pp -= row;
        }
        const float f = (i == j) ? 1.f : 2.f;
        float acc = 0.f;
#pragma unroll
        for (int kk = 0; kk < DIM; ++kk) {
            const float zq = ((kk >> (3 - q)) & 1) ? -1.f : 1.f;
            acc += zq * (Ure[kk][i] * Ure[kk][j] + Uim[kk][i] * Uim[kk][j]);
        }
        ApackS[d] = f * acc;
    }
    __syncthreads();

    // ---- phase 2: one batch row per thread ----
    const long long b = (long long)blockIdx.x * TPB + tid;
    if (b >= B) return;

    float acc[NQ];
#pragma unroll
    for (int q = 0; q < NQ; ++q) acc[q] = fm_b[q];

    const float4* __restrict__ x4 = (const float4*)(x + b * 64);
    const float4* __restrict__ w4 = (const float4*)fm_w;
#pragma unroll
    for (int t = 0; t < 16; ++t) {
        const float4 xv = x4[t];
#pragma unroll
        for (int q = 0; q < NQ; ++q) {
            const float4 wv = w4[q * 16 + t];  // uniform -> scalar loads
            acc[q] += xv.x * wv.x + xv.y * wv.y + xv.z * wv.z + xv.w * wv.w;
        }
    }

    float c[NQ], s[NQ];
#pragma unroll
    for (int q = 0; q < NQ; ++q) __sincosf(0.5f * acc[q], &s[q], &c[q]);

    float p01[4], p23[4];
#pragma unroll
    for (int u = 0; u < 4; ++u) {
        p01[u] = ((u & 2) ? s[0] : c[0]) * ((u & 1) ? s[1] : c[1]);
        p23[u] = ((u & 2) ? s[2] : c[2]) * ((u & 1) ? s[3] : c[3]);
    }
    float st[DIM];
#pragma unroll
    for (int i = 0; i < DIM; ++i) st[i] = p01[i >> 2] * p23[i & 3];

    float o0 = 0.f, o1 = 0.f, o2 = 0.f, o3 = 0.f;
    const float4* __restrict__ A4 = (const float4*)ApackS;
    int p = 0;
#pragma unroll
    for (int i = 0; i < DIM; ++i) {
#pragma unroll
        for (int j = i; j < DIM; ++j) {
            const float pr = st[i] * st[j];
            const float4 aq = A4[p];   // uniform LDS -> broadcast ds_read_b128
            o0 += aq.x * pr; o1 += aq.y * pr; o2 += aq.z * pr; o3 += aq.w * pr;
            ++p;
        }
    }

    *(float4*)(out + b * 4) = make_float4(o0, o1, o2, o3);
}

extern "C" void kernel_launch(void* const* d_in, const int* in_sizes, int n_in,
                              void* d_out, int out_size, void* d_ws, size_t ws_size,
                              hipStream_t stream) {
    const float* x    = (const float*)d_in[0];
    const float* fm_w = (const float*)d_in[1];
    const float* fm_b = (const float*)d_in[2];
    const float* qw   = (const float*)d_in[3];
    float* out = (float*)d_out;

    const int B = in_sizes[0] / 64;

    qnn_fused<<<(B + TPB - 1) / TPB, TPB, 0, stream>>>(x, fm_w, fm_b, qw, out, B);
}